// Round 2
// baseline (496.338 us; speedup 1.0000x reference)
//
#include <hip/hip_runtime.h>
#include <stdint.h>

typedef __bf16 bf16x8 __attribute__((ext_vector_type(8)));
typedef float f32x4 __attribute__((ext_vector_type(4)));

__device__ __forceinline__ float bf2f(uint16_t u) {
  union { uint32_t i; float f; } v; v.i = ((uint32_t)u) << 16; return v.f;
}
__device__ __forceinline__ uint16_t f2bf(float f) {
  union { float f; uint32_t i; } v; v.f = f;
  uint32_t u = v.i;
  uint32_t r = (u + 0x7FFFu + ((u >> 16) & 1u)) >> 16;
  return (uint16_t)r;
}

// ---------------------------------------------------------------------------
// Kernel 0: convert fc1/fc2 weights fp32 -> bf16 into workspace (re-done every
// call since ws is re-poisoned). 262144 elems each.
// ---------------------------------------------------------------------------
__global__ __launch_bounds__(256) void cvt_weights_kernel(
    const float* __restrict__ fc1, const float* __restrict__ fc2,
    uint16_t* __restrict__ fc1b, uint16_t* __restrict__ fc2b)
{
  int i = (blockIdx.x * 256 + threadIdx.x) * 4;   // grid covers 262144/4*2
  if (i < 262144) {
    float4 a = *(const float4*)(fc1 + i);
    ushort4 o;
    o.x = f2bf(a.x); o.y = f2bf(a.y); o.z = f2bf(a.z); o.w = f2bf(a.w);
    *(ushort4*)(fc1b + i) = o;
  } else {
    int j = i - 262144;
    float4 a = *(const float4*)(fc2 + j);
    ushort4 o;
    o.x = f2bf(a.x); o.y = f2bf(a.y); o.z = f2bf(a.z); o.w = f2bf(a.w);
    *(ushort4*)(fc2b + j) = o;
  }
}

// ---------------------------------------------------------------------------
// Kernel 1: NeoCell (block-diagonal A·X·B per channel) + BatchNorm(eval).
// x: NCHW fp32 (32,256,56,56) -> y1: (100352 x 256) row-major bf16 (NHWC).
// Block: 128 threads = 128 channels (blockIdx.z selects k=2 half or k=4 half,
// so the k-branch is block-uniform). One block handles a 4-row strip of one
// image for its 128 channels. x staged fp32->bf16 into LDS (stride 226 elems
// -> odd dword stride -> conflict-light). Writes: lanes = consecutive
// channels at one pixel -> fully coalesced stores.
// ---------------------------------------------------------------------------
__global__ __launch_bounds__(128) void neocell_bn_kernel(
    const float* __restrict__ x,
    const float* __restrict__ wa1, const float* __restrict__ wb1,
    const float* __restrict__ wa2, const float* __restrict__ wb2,
    const float* __restrict__ bnw, const float* __restrict__ bnb,
    const float* __restrict__ bnm, const float* __restrict__ bnv,
    uint16_t* __restrict__ y1)
{
  __shared__ uint16_t lx[128 * 226];
  const int t = threadIdx.x;        // 0..127
  const int strip = blockIdx.x;     // 0..13 (4-row strips)
  const int b = blockIdx.y;         // 0..31
  const int half = blockIdx.z;      // 0: k=2 channels, 1: k=4 channels
  const int h0 = strip * 4;

  // Stage 128 channels x (4 rows x 56 cols = 224 floats, contiguous per chan)
  // as bf16. 224 floats = 56 float4 chunks per channel; 7168 chunks / 128
  // threads = 56 iters. Reads fully coalesced (16B/lane).
  for (int i = 0; i < 56; ++i) {
    int l = t + i * 128;            // 0..7167
    int c = l / 56;
    int r = l - c * 56;
    const float* g = x + (size_t)(b * 256 + half * 128 + c) * 3136
                       + h0 * 56 + r * 4;
    float4 v = *(const float4*)g;
    ushort4 o;
    o.x = f2bf(v.x); o.y = f2bf(v.y); o.z = f2bf(v.z); o.w = f2bf(v.w);
    *(ushort4*)(lx + c * 226 + r * 4) = o;
  }
  __syncthreads();

  const int c = half * 128 + t;     // global channel
  const float scale = bnw[c] * rsqrtf(bnv[c] + 1e-5f);
  const float shift = bnb[c] - bnm[c] * scale;
  const uint16_t* lc = lx + t * 226;
  const size_t prow0 = (size_t)b * 56;

  if (half == 0) {
    // k = 2: strip holds two 2-row block rows, 28 block cols.
    float A[2][2], Bm[2][2];
#pragma unroll
    for (int p = 0; p < 2; ++p)
#pragma unroll
      for (int i = 0; i < 2; ++i) A[p][i] = wa1[t * 4 + p * 2 + i];
#pragma unroll
    for (int j = 0; j < 2; ++j)
#pragma unroll
      for (int q = 0; q < 2; ++q) Bm[j][q] = wb1[t * 4 + j * 2 + q];

    for (int n2 = 0; n2 < 2; ++n2) {
      for (int m = 0; m < 28; ++m) {
        float X[2][2], T[2][2];
#pragma unroll
        for (int i = 0; i < 2; ++i)
#pragma unroll
          for (int j = 0; j < 2; ++j)
            X[i][j] = bf2f(lc[(n2 * 2 + i) * 56 + m * 2 + j]);
#pragma unroll
        for (int p = 0; p < 2; ++p)
#pragma unroll
          for (int j = 0; j < 2; ++j)
            T[p][j] = A[p][0] * X[0][j] + A[p][1] * X[1][j];
#pragma unroll
        for (int p = 0; p < 2; ++p)
#pragma unroll
          for (int q = 0; q < 2; ++q) {
            float v = T[p][0] * Bm[0][q] + T[p][1] * Bm[1][q];
            v = v * scale + shift;
            size_t pix = (prow0 + h0 + n2 * 2 + p) * 56 + (m * 2 + q);
            y1[pix * 256 + c] = f2bf(v);
          }
      }
    }
  } else {
    // k = 4: one 4-row block row, 14 block cols.
    float A[4][4], Bm[4][4];
#pragma unroll
    for (int p = 0; p < 4; ++p)
#pragma unroll
      for (int i = 0; i < 4; ++i) A[p][i] = wa2[t * 16 + p * 4 + i];
#pragma unroll
    for (int j = 0; j < 4; ++j)
#pragma unroll
      for (int q = 0; q < 4; ++q) Bm[j][q] = wb2[t * 16 + j * 4 + q];

    for (int m = 0; m < 14; ++m) {
      float X[4][4], T[4][4];
#pragma unroll
      for (int i = 0; i < 4; ++i)
#pragma unroll
        for (int j = 0; j < 4; ++j)
          X[i][j] = bf2f(lc[i * 56 + m * 4 + j]);
#pragma unroll
      for (int p = 0; p < 4; ++p)
#pragma unroll
        for (int j = 0; j < 4; ++j)
          T[p][j] = A[p][0] * X[0][j] + A[p][1] * X[1][j]
                  + A[p][2] * X[2][j] + A[p][3] * X[3][j];
#pragma unroll
      for (int p = 0; p < 4; ++p)
#pragma unroll
        for (int q = 0; q < 4; ++q) {
          float v = T[p][0] * Bm[0][q] + T[p][1] * Bm[1][q]
                  + T[p][2] * Bm[2][q] + T[p][3] * Bm[3][q];
          v = v * scale + shift;
          size_t pix = (prow0 + h0 + p) * 56 + (m * 4 + q);
          y1[pix * 256 + c] = f2bf(v);
        }
    }
  }
}

// ---------------------------------------------------------------------------
// m97-style GEMM: C[row][col] = sum_k A[row][k] * B[col][k]   (both K-contig,
// bf16). 128x128 tile, BK=32, 4 waves in 2x2, each wave 64x64 = 4x4 of
// 16x16x32 MFMAs. global_load_lds width=16, single LDS buffer, 2-barrier
// K-loop (verified m97 structure).
// EPI 0: exact GELU -> Cb16 is h (rows x 1024 bf16), col base=blockIdx.y*128.
// EPI 1: LDS-transpose epilogue -> NCHW fp32 out with fused residual (fp32).
// ---------------------------------------------------------------------------
template <int KD, int EPI>
__global__ __launch_bounds__(256) void gemm_bt_kernel(
    const uint16_t* __restrict__ A,     // rows x KD, row-major bf16
    const uint16_t* __restrict__ Bw,    // cols x KD, row-major bf16
    uint16_t* __restrict__ Cb16,        // EPI0 output (bf16)
    float* __restrict__ Cf32,           // EPI1 output (fp32 NCHW)
    const float* __restrict__ Xres,     // EPI1: residual (NCHW fp32)
    int chunk_pix0)                     // EPI1: global pixel offset of chunk
{
  __shared__ uint16_t lds[16640];       // K-loop: A[0..4096), B[4096..8192)
  uint16_t* ldsA = lds;                 // epilogue(EPI1): 128x130 bf16 tile
  uint16_t* ldsB = lds + 4096;

  const int tid = threadIdx.x;
  const int lane = tid & 63;
  const int wid = tid >> 6;
  const int wm = wid & 1;
  const int wn = wid >> 1;
  const int fm = lane & 15;             // MFMA row/col within 16
  const int fq = lane >> 4;             // quad

  const size_t arow0 = (size_t)blockIdx.x * 128;
  const size_t brow0 = (size_t)blockIdx.y * 128;

  f32x4 acc[4][4];
#pragma unroll
  for (int i = 0; i < 4; ++i)
#pragma unroll
    for (int j = 0; j < 4; ++j) { f32x4 z = {0.f, 0.f, 0.f, 0.f}; acc[i][j] = z; }

  // Staging map: chunk q in [0,512): row = q>>2, 16B piece kk = q&3.
  // LDS elem offset = q*8 -> row-major [128][32], matching the wave-uniform
  // base + lane*16 landing pattern of global_load_lds.
  const int q0 = tid, q1 = tid + 256;
  const int r0 = q0 >> 2, kk0 = q0 & 3;
  const int r1 = q1 >> 2, kk1 = q1 & 3;
  const uint16_t* a0 = A + (arow0 + r0) * KD + kk0 * 8;
  const uint16_t* a1 = A + (arow0 + r1) * KD + kk1 * 8;
  const uint16_t* b0 = Bw + (brow0 + r0) * KD + kk0 * 8;
  const uint16_t* b1 = Bw + (brow0 + r1) * KD + kk1 * 8;

  for (int k0 = 0; k0 < KD; k0 += 32) {
    __syncthreads();  // LDS free (compiler drains lgkm before barrier)
    __builtin_amdgcn_global_load_lds(
        (const __attribute__((address_space(1))) void*)(a0 + k0),
        (__attribute__((address_space(3))) void*)(ldsA + q0 * 8), 16, 0, 0);
    __builtin_amdgcn_global_load_lds(
        (const __attribute__((address_space(1))) void*)(a1 + k0),
        (__attribute__((address_space(3))) void*)(ldsA + q1 * 8), 16, 0, 0);
    __builtin_amdgcn_global_load_lds(
        (const __attribute__((address_space(1))) void*)(b0 + k0),
        (__attribute__((address_space(3))) void*)(ldsB + q0 * 8), 16, 0, 0);
    __builtin_amdgcn_global_load_lds(
        (const __attribute__((address_space(1))) void*)(b1 + k0),
        (__attribute__((address_space(3))) void*)(ldsB + q1 * 8), 16, 0, 0);
    __syncthreads();  // vmcnt(0) drain + barrier

    bf16x8 af[4], bfr[4];
#pragma unroll
    for (int mt = 0; mt < 4; ++mt)
      af[mt] = *(const bf16x8*)(const void*)
               (ldsA + (wm * 64 + mt * 16 + fm) * 32 + fq * 8);
#pragma unroll
    for (int nt = 0; nt < 4; ++nt)
      bfr[nt] = *(const bf16x8*)(const void*)
                (ldsB + (wn * 64 + nt * 16 + fm) * 32 + fq * 8);
#pragma unroll
    for (int mt = 0; mt < 4; ++mt)
#pragma unroll
      for (int nt = 0; nt < 4; ++nt)
        acc[mt][nt] = __builtin_amdgcn_mfma_f32_16x16x32_bf16(
            af[mt], bfr[nt], acc[mt][nt], 0, 0, 0);
  }

  if (EPI == 0) {
    // GELU(exact) -> h, row-major (rows x 1024) bf16.
    // D layout: col=lane&15, row=fq*4+r (m89/m91 verified).
#pragma unroll
    for (int mt = 0; mt < 4; ++mt) {
      const size_t rb = arow0 + wm * 64 + mt * 16 + fq * 4;
#pragma unroll
      for (int nt = 0; nt < 4; ++nt) {
        const size_t n = brow0 + wn * 64 + nt * 16 + fm;
#pragma unroll
        for (int r = 0; r < 4; ++r) {
          float v = acc[mt][nt][r];
          v = 0.5f * v * (1.0f + erff(v * 0.70710678118654752f));
          Cb16[(rb + r) * 1024 + n] = f2bf(v);
        }
      }
    }
  } else {
    // Transpose through LDS so NCHW stores are pixel-contiguous (coalesced),
    // with fused residual (residual address == output address).
    __syncthreads();
#pragma unroll
    for (int mt = 0; mt < 4; ++mt) {
      int mbase = wm * 64 + mt * 16 + fq * 4;     // pixel within tile
#pragma unroll
      for (int nt = 0; nt < 4; ++nt) {
        int n = wn * 64 + nt * 16 + fm;           // channel within tile
#pragma unroll
        for (int r = 0; r < 4; ++r)
          lds[n * 130 + mbase + r] = f2bf(acc[mt][nt][r]);
      }
    }
    __syncthreads();
    const int pl0 = tid & 31;
    const int cw = tid >> 5;
#pragma unroll
    for (int it = 0; it < 16; ++it) {
      int ch = cw + it * 8;                        // channel within tile
      int cgl = (int)brow0 + ch;                   // global channel
#pragma unroll
      for (int e = 0; e < 4; ++e) {
        int pl = pl0 + e * 32;                     // pixel within tile
        uint32_t pg = (uint32_t)(chunk_pix0) + blockIdx.x * 128u + (uint32_t)pl;
        uint32_t bimg = pg / 3136u;                // image index
        uint32_t rem = pg - bimg * 3136u;          // h*56+w
        size_t addr = ((size_t)bimg * 256 + cgl) * 3136 + rem;
        Cf32[addr] = bf2f(lds[ch * 130 + pl]) + Xres[addr];
      }
    }
  }
}

// ---------------------------------------------------------------------------
// Launch: cvt weights -> K1 -> y1 (ws). Then chunked over pixel tiles (sized
// by ws_size):
//   GEMM1 (K=256)  y1 @ fc1^T -> gelu -> h (bf16, ws)
//   GEMM2 (K=1024) h @ fc2^T + x -> out (fp32 NCHW)
// ---------------------------------------------------------------------------
extern "C" void kernel_launch(void* const* d_in, const int* in_sizes, int n_in,
                              void* d_out, int out_size, void* d_ws,
                              size_t ws_size, hipStream_t stream)
{
  const float* x   = (const float*)d_in[0];
  const float* wa1 = (const float*)d_in[1];
  const float* wb1 = (const float*)d_in[2];
  const float* wa2 = (const float*)d_in[3];
  const float* wb2 = (const float*)d_in[4];
  const float* bnw = (const float*)d_in[5];
  const float* bnb = (const float*)d_in[6];
  const float* bnm = (const float*)d_in[7];
  const float* bnv = (const float*)d_in[8];
  const float* fc1 = (const float*)d_in[9];
  const float* fc2 = (const float*)d_in[10];
  float* out = (float*)d_out;

  uint16_t* fc1b = (uint16_t*)d_ws;                 // 262144 u16 = 512 KB
  uint16_t* fc2b = fc1b + 262144;                   // 512 KB
  uint16_t* y1 = fc2b + 262144;                     // 100352*256*2 = 51.4 MB
  const size_t y1_elems = (size_t)100352 * 256;
  uint16_t* h = y1 + y1_elems;

  const long tiles_total = 784;                     // 100352 / 128
  const size_t fixed_bytes = (size_t)262144 * 4 + y1_elems * 2;
  long tiles_chunk = 1;
  if (ws_size > fixed_bytes + 262144) {
    tiles_chunk = (long)((ws_size - fixed_bytes) / (128ul * 1024ul * 2ul));
    if (tiles_chunk > tiles_total) tiles_chunk = tiles_total;
    if (tiles_chunk < 1) tiles_chunk = 1;
  }

  cvt_weights_kernel<<<512, 256, 0, stream>>>(fc1, fc2, fc1b, fc2b);
  neocell_bn_kernel<<<dim3(14, 32, 2), 128, 0, stream>>>(
      x, wa1, wb1, wa2, wb2, bnw, bnb, bnm, bnv, y1);

  for (long t0 = 0; t0 < tiles_total; t0 += tiles_chunk) {
    long T = tiles_total - t0;
    if (T > tiles_chunk) T = tiles_chunk;
    gemm_bt_kernel<256, 0><<<dim3((uint32_t)T, 8), 256, 0, stream>>>(
        y1 + (size_t)t0 * 128 * 256, fc1b, h, nullptr, nullptr, 0);
    gemm_bt_kernel<1024, 1><<<dim3((uint32_t)T, 2), 256, 0, stream>>>(
        h, fc2b, nullptr, out, x, (int)(t0 * 128));
  }
}

// Round 3
// 443.056 us; speedup vs baseline: 1.1203x; 1.1203x over previous
//
#include <hip/hip_runtime.h>
#include <stdint.h>

typedef __bf16 bf16x8 __attribute__((ext_vector_type(8)));
typedef float f32x4 __attribute__((ext_vector_type(4)));

__device__ __forceinline__ float bf2f(uint16_t u) {
  union { uint32_t i; float f; } v; v.i = ((uint32_t)u) << 16; return v.f;
}
__device__ __forceinline__ uint16_t f2bf(float f) {
  union { float f; uint32_t i; } v; v.f = f;
  uint32_t u = v.i;
  uint32_t r = (u + 0x7FFFu + ((u >> 16) & 1u)) >> 16;
  return (uint16_t)r;
}
// gelu(v) = v * sigmoid(1.5957691*v*(1+0.044715*v^2))  (tanh-form identity).
// ~8 VALU ops, hw exp/rcp, branchless. |gelu_tanh - gelu_erf| <~ 1e-3.
__device__ __forceinline__ float fast_gelu(float v) {
  float t2 = v * v;
  float pz = 1.0f + 0.044715f * t2;
  float w = -1.5957691216f * v * pz;
  float e = __expf(w);
  return v * __builtin_amdgcn_rcpf(1.0f + e);
}

// ---------------------------------------------------------------------------
// Kernel 0: convert fc1/fc2 weights fp32 -> bf16 into workspace (ws is
// re-poisoned every call, so redo each launch). 262144 elems each.
// ---------------------------------------------------------------------------
__global__ __launch_bounds__(256) void cvt_weights_kernel(
    const float* __restrict__ fc1, const float* __restrict__ fc2,
    uint16_t* __restrict__ fc1b, uint16_t* __restrict__ fc2b)
{
  int i = (blockIdx.x * 256 + threadIdx.x) * 4;
  if (i < 262144) {
    float4 a = *(const float4*)(fc1 + i);
    ushort4 o;
    o.x = f2bf(a.x); o.y = f2bf(a.y); o.z = f2bf(a.z); o.w = f2bf(a.w);
    *(ushort4*)(fc1b + i) = o;
  } else {
    int j = i - 262144;
    float4 a = *(const float4*)(fc2 + j);
    ushort4 o;
    o.x = f2bf(a.x); o.y = f2bf(a.y); o.z = f2bf(a.z); o.w = f2bf(a.w);
    *(ushort4*)(fc2b + j) = o;
  }
}

// ---------------------------------------------------------------------------
// Kernel 1: NeoCell (block-diagonal A·X·B per channel) + BatchNorm(eval).
// x: NCHW fp32 (32,256,56,56) -> y1: (100352 x 256) row-major bf16 (NHWC).
// Each thread handles a PAIR of adjacent channels so y1 stores pack into u32
// (wave writes 256 B contiguous). blockIdx.z selects the k=2 / k=4 half so
// the k branch is block-uniform. LDS stride 226 (odd dword stride) keeps
// compute-phase reads conflict-free.
// ---------------------------------------------------------------------------
__global__ __launch_bounds__(128) void neocell_bn_kernel(
    const float* __restrict__ x,
    const float* __restrict__ wa1, const float* __restrict__ wb1,
    const float* __restrict__ wa2, const float* __restrict__ wb2,
    const float* __restrict__ bnw, const float* __restrict__ bnb,
    const float* __restrict__ bnm, const float* __restrict__ bnv,
    uint16_t* __restrict__ y1)
{
  __shared__ uint16_t lx[128 * 226];
  const int t = threadIdx.x;        // 0..127
  const int strip = blockIdx.x;     // 0..13 (4-row strips)
  const int b = blockIdx.y;         // 0..31
  const int half = blockIdx.z;      // 0: k=2 channels, 1: k=4 channels
  const int h0 = strip * 4;

  // Stage 128 channels x (4 rows x 56 cols) fp32 -> bf16 into LDS.
  for (int i = 0; i < 56; ++i) {
    int l = t + i * 128;            // 0..7167
    int c = l / 56;
    int r = l - c * 56;
    const float* g = x + (size_t)(b * 256 + half * 128 + c) * 3136
                       + h0 * 56 + r * 4;
    float4 v = *(const float4*)g;
    ushort4 o;
    o.x = f2bf(v.x); o.y = f2bf(v.y); o.z = f2bf(v.z); o.w = f2bf(v.w);
    *(ushort4*)(lx + c * 226 + r * 4) = o;
  }
  __syncthreads();

  const int a = t & 63;             // channel-pair index (local ch 2a, 2a+1)
  const int p = t >> 6;             // sub-partition (rows for k=2, cols k=4)
  const int c0 = half * 128 + 2 * a;

  float sc[2], sh[2];
#pragma unroll
  for (int ch = 0; ch < 2; ++ch) {
    int cg = c0 + ch;
    sc[ch] = bnw[cg] * rsqrtf(bnv[cg] + 1e-5f);
    sh[ch] = bnb[cg] - bnm[cg] * sc[ch];
  }
  const size_t pgbase = (size_t)b * 3136 + (size_t)h0 * 56;

  if (half == 0) {
    // k=2. Thread: channels 2a,2a+1; strip rows {2p,2p+1}; all 28 block cols.
    float A[2][2][2], Bm[2][2][2];
#pragma unroll
    for (int ch = 0; ch < 2; ++ch)
#pragma unroll
      for (int i = 0; i < 2; ++i)
#pragma unroll
        for (int j = 0; j < 2; ++j) {
          A[ch][i][j]  = wa1[(2 * a + ch) * 4 + i * 2 + j];
          Bm[ch][i][j] = wb1[(2 * a + ch) * 4 + i * 2 + j];
        }
    for (int m = 0; m < 28; ++m) {
      float O[2][2][2];   // [ch][row][col]
#pragma unroll
      for (int ch = 0; ch < 2; ++ch) {
        const uint16_t* lc = lx + (2 * a + ch) * 226 + (2 * p) * 56 + m * 2;
        uint32_t w0 = *(const uint32_t*)lc;
        uint32_t w1 = *(const uint32_t*)(lc + 56);
        float X[2][2];
        X[0][0] = bf2f((uint16_t)w0); X[0][1] = bf2f((uint16_t)(w0 >> 16));
        X[1][0] = bf2f((uint16_t)w1); X[1][1] = bf2f((uint16_t)(w1 >> 16));
        float T[2][2];
#pragma unroll
        for (int pp = 0; pp < 2; ++pp)
#pragma unroll
          for (int j = 0; j < 2; ++j)
            T[pp][j] = A[ch][pp][0] * X[0][j] + A[ch][pp][1] * X[1][j];
#pragma unroll
        for (int pp = 0; pp < 2; ++pp)
#pragma unroll
          for (int q = 0; q < 2; ++q)
            O[ch][pp][q] = (T[pp][0] * Bm[ch][0][q] + T[pp][1] * Bm[ch][1][q])
                           * sc[ch] + sh[ch];
      }
#pragma unroll
      for (int pp = 0; pp < 2; ++pp)
#pragma unroll
        for (int q = 0; q < 2; ++q) {
          uint32_t pk = (uint32_t)f2bf(O[0][pp][q])
                      | ((uint32_t)f2bf(O[1][pp][q]) << 16);
          size_t pg = pgbase + (size_t)(2 * p + pp) * 56 + (m * 2 + q);
          *(uint32_t*)(y1 + pg * 256 + c0) = pk;
        }
    }
  } else {
    // k=4. Thread: channels 2a,2a+1; all 4 strip rows; block cols m=2*mm+p.
    float A[2][4][4], Bm[2][4][4];
#pragma unroll
    for (int ch = 0; ch < 2; ++ch)
#pragma unroll
      for (int i = 0; i < 4; ++i)
#pragma unroll
        for (int j = 0; j < 4; ++j) {
          A[ch][i][j]  = wa2[(2 * a + ch) * 16 + i * 4 + j];
          Bm[ch][i][j] = wb2[(2 * a + ch) * 16 + i * 4 + j];
        }
    for (int mm = 0; mm < 7; ++mm) {
      int m = 2 * mm + p;
      float O[2][4][4];
#pragma unroll
      for (int ch = 0; ch < 2; ++ch) {
        float X[4][4];
#pragma unroll
        for (int i = 0; i < 4; ++i) {
          const uint16_t* lc = lx + (2 * a + ch) * 226 + i * 56 + m * 4;
          uint32_t w0 = *(const uint32_t*)lc;
          uint32_t w1 = *(const uint32_t*)(lc + 2);
          X[i][0] = bf2f((uint16_t)w0); X[i][1] = bf2f((uint16_t)(w0 >> 16));
          X[i][2] = bf2f((uint16_t)w1); X[i][3] = bf2f((uint16_t)(w1 >> 16));
        }
        float T[4][4];
#pragma unroll
        for (int pp = 0; pp < 4; ++pp)
#pragma unroll
          for (int j = 0; j < 4; ++j)
            T[pp][j] = A[ch][pp][0] * X[0][j] + A[ch][pp][1] * X[1][j]
                     + A[ch][pp][2] * X[2][j] + A[ch][pp][3] * X[3][j];
#pragma unroll
        for (int pp = 0; pp < 4; ++pp)
#pragma unroll
          for (int q = 0; q < 4; ++q)
            O[ch][pp][q] = (T[pp][0] * Bm[ch][0][q] + T[pp][1] * Bm[ch][1][q]
                          + T[pp][2] * Bm[ch][2][q] + T[pp][3] * Bm[ch][3][q])
                           * sc[ch] + sh[ch];
      }
#pragma unroll
      for (int pp = 0; pp < 4; ++pp)
#pragma unroll
        for (int q = 0; q < 4; ++q) {
          uint32_t pk = (uint32_t)f2bf(O[0][pp][q])
                      | ((uint32_t)f2bf(O[1][pp][q]) << 16);
          size_t pg = pgbase + (size_t)pp * 56 + (m * 4 + q);
          *(uint32_t*)(y1 + pg * 256 + c0) = pk;
        }
    }
  }
}

// ---------------------------------------------------------------------------
// m97-style GEMM: C[row][col] = sum_k A[row][k] * B[col][k]   (both K-contig,
// bf16). 128x128 tile, BK=32, 4 waves 2x2, 4x4 of 16x16x32 MFMAs/wave,
// global_load_lds width=16, 2-barrier K-loop.
// GRID: blockIdx.x = COL block (fast axis -> consecutive blocks share the
// A-tile in L2; fc weights pin in L2), blockIdx.y = pixel tile.
// EPI 0: fast GELU -> h (rows x 1024 bf16).
// EPI 1: LDS-transpose epilogue -> NCHW fp32 out + fused fp32 residual.
// ---------------------------------------------------------------------------
template <int KD, int EPI>
__global__ __launch_bounds__(256) void gemm_bt_kernel(
    const uint16_t* __restrict__ A,     // rows x KD, row-major bf16
    const uint16_t* __restrict__ Bw,    // cols x KD, row-major bf16
    uint16_t* __restrict__ Cb16,        // EPI0 output (bf16)
    float* __restrict__ Cf32,           // EPI1 output (fp32 NCHW)
    const float* __restrict__ Xres,     // EPI1: residual (NCHW fp32)
    int chunk_pix0)                     // EPI1: global pixel offset of chunk
{
  __shared__ uint16_t lds[16640];       // K-loop: A[0..4096), B[4096..8192)
  uint16_t* ldsA = lds;                 // epilogue(EPI1): 128x130 bf16 tile
  uint16_t* ldsB = lds + 4096;

  const int tid = threadIdx.x;
  const int lane = tid & 63;
  const int wid = tid >> 6;
  const int wm = wid & 1;
  const int wn = wid >> 1;
  const int fm = lane & 15;             // MFMA row/col within 16
  const int fq = lane >> 4;             // quad

  const size_t arow0 = (size_t)blockIdx.y * 128;   // pixel-tile base
  const size_t brow0 = (size_t)blockIdx.x * 128;   // col-block base

  f32x4 acc[4][4];
#pragma unroll
  for (int i = 0; i < 4; ++i)
#pragma unroll
    for (int j = 0; j < 4; ++j) { f32x4 z = {0.f, 0.f, 0.f, 0.f}; acc[i][j] = z; }

  const int q0 = tid, q1 = tid + 256;
  const int r0 = q0 >> 2, kk0 = q0 & 3;
  const int r1 = q1 >> 2, kk1 = q1 & 3;
  const uint16_t* a0 = A + (arow0 + r0) * KD + kk0 * 8;
  const uint16_t* a1 = A + (arow0 + r1) * KD + kk1 * 8;
  const uint16_t* b0 = Bw + (brow0 + r0) * KD + kk0 * 8;
  const uint16_t* b1 = Bw + (brow0 + r1) * KD + kk1 * 8;

  for (int k0 = 0; k0 < KD; k0 += 32) {
    __syncthreads();
    __builtin_amdgcn_global_load_lds(
        (const __attribute__((address_space(1))) void*)(a0 + k0),
        (__attribute__((address_space(3))) void*)(ldsA + q0 * 8), 16, 0, 0);
    __builtin_amdgcn_global_load_lds(
        (const __attribute__((address_space(1))) void*)(a1 + k0),
        (__attribute__((address_space(3))) void*)(ldsA + q1 * 8), 16, 0, 0);
    __builtin_amdgcn_global_load_lds(
        (const __attribute__((address_space(1))) void*)(b0 + k0),
        (__attribute__((address_space(3))) void*)(ldsB + q0 * 8), 16, 0, 0);
    __builtin_amdgcn_global_load_lds(
        (const __attribute__((address_space(1))) void*)(b1 + k0),
        (__attribute__((address_space(3))) void*)(ldsB + q1 * 8), 16, 0, 0);
    __syncthreads();

    bf16x8 af[4], bfr[4];
#pragma unroll
    for (int mt = 0; mt < 4; ++mt)
      af[mt] = *(const bf16x8*)(const void*)
               (ldsA + (wm * 64 + mt * 16 + fm) * 32 + fq * 8);
#pragma unroll
    for (int nt = 0; nt < 4; ++nt)
      bfr[nt] = *(const bf16x8*)(const void*)
                (ldsB + (wn * 64 + nt * 16 + fm) * 32 + fq * 8);
#pragma unroll
    for (int mt = 0; mt < 4; ++mt)
#pragma unroll
      for (int nt = 0; nt < 4; ++nt)
        acc[mt][nt] = __builtin_amdgcn_mfma_f32_16x16x32_bf16(
            af[mt], bfr[nt], acc[mt][nt], 0, 0, 0);
  }

  if (EPI == 0) {
    // fast GELU -> h, row-major (rows x 1024) bf16.
    // D layout: col=lane&15, row=fq*4+r (m89/m91 verified).
#pragma unroll
    for (int mt = 0; mt < 4; ++mt) {
      const size_t rb = arow0 + wm * 64 + mt * 16 + fq * 4;
#pragma unroll
      for (int nt = 0; nt < 4; ++nt) {
        const size_t n = brow0 + wn * 64 + nt * 16 + fm;
#pragma unroll
        for (int r = 0; r < 4; ++r)
          Cb16[(rb + r) * 1024 + n] = f2bf(fast_gelu(acc[mt][nt][r]));
      }
    }
  } else {
    // Transpose through LDS -> pixel-contiguous NCHW fp32 stores + residual.
    __syncthreads();
#pragma unroll
    for (int mt = 0; mt < 4; ++mt) {
      int mbase = wm * 64 + mt * 16 + fq * 4;     // pixel within tile
#pragma unroll
      for (int nt = 0; nt < 4; ++nt) {
        int n = wn * 64 + nt * 16 + fm;           // channel within tile
#pragma unroll
        for (int r = 0; r < 4; ++r)
          lds[n * 130 + mbase + r] = f2bf(acc[mt][nt][r]);
      }
    }
    __syncthreads();
    const int pl0 = tid & 31;
    const int cw = tid >> 5;
#pragma unroll
    for (int it = 0; it < 16; ++it) {
      int ch = cw + it * 8;                        // channel within tile
      int cgl = (int)brow0 + ch;                   // global channel
#pragma unroll
      for (int e = 0; e < 4; ++e) {
        int pl = pl0 + e * 32;                     // pixel within tile
        uint32_t pg = (uint32_t)chunk_pix0 + blockIdx.y * 128u + (uint32_t)pl;
        uint32_t bimg = pg / 3136u;
        uint32_t rem = pg - bimg * 3136u;
        size_t addr = ((size_t)bimg * 256 + cgl) * 3136 + rem;
        Cf32[addr] = bf2f(lds[ch * 130 + pl]) + Xres[addr];
      }
    }
  }
}

// ---------------------------------------------------------------------------
// Launch: cvt weights -> neocell -> y1 (ws). Then chunked over pixel tiles:
//   GEMM1 (K=256)  y1 @ fc1^T -> gelu -> h (bf16, ws)
//   GEMM2 (K=1024) h @ fc2^T + x -> out (fp32 NCHW)
// ---------------------------------------------------------------------------
extern "C" void kernel_launch(void* const* d_in, const int* in_sizes, int n_in,
                              void* d_out, int out_size, void* d_ws,
                              size_t ws_size, hipStream_t stream)
{
  const float* x   = (const float*)d_in[0];
  const float* wa1 = (const float*)d_in[1];
  const float* wb1 = (const float*)d_in[2];
  const float* wa2 = (const float*)d_in[3];
  const float* wb2 = (const float*)d_in[4];
  const float* bnw = (const float*)d_in[5];
  const float* bnb = (const float*)d_in[6];
  const float* bnm = (const float*)d_in[7];
  const float* bnv = (const float*)d_in[8];
  const float* fc1 = (const float*)d_in[9];
  const float* fc2 = (const float*)d_in[10];
  float* out = (float*)d_out;

  uint16_t* fc1b = (uint16_t*)d_ws;                 // 512 KB
  uint16_t* fc2b = fc1b + 262144;                   // 512 KB
  uint16_t* y1 = fc2b + 262144;                     // 51.4 MB
  const size_t y1_elems = (size_t)100352 * 256;
  uint16_t* h = y1 + y1_elems;

  const long tiles_total = 784;                     // 100352 / 128
  const size_t fixed_bytes = (size_t)262144 * 4 + y1_elems * 2;
  long tiles_chunk = 1;
  if (ws_size > fixed_bytes + 262144) {
    tiles_chunk = (long)((ws_size - fixed_bytes) / (128ul * 1024ul * 2ul));
    if (tiles_chunk > tiles_total) tiles_chunk = tiles_total;
    if (tiles_chunk < 1) tiles_chunk = 1;
  }

  cvt_weights_kernel<<<512, 256, 0, stream>>>(fc1, fc2, fc1b, fc2b);
  neocell_bn_kernel<<<dim3(14, 32, 2), 128, 0, stream>>>(
      x, wa1, wb1, wa2, wb2, bnw, bnb, bnm, bnv, y1);

  for (long t0 = 0; t0 < tiles_total; t0 += tiles_chunk) {
    long T = tiles_total - t0;
    if (T > tiles_chunk) T = tiles_chunk;
    gemm_bt_kernel<256, 0><<<dim3(8, (uint32_t)T), 256, 0, stream>>>(
        y1 + (size_t)t0 * 128 * 256, fc1b, h, nullptr, nullptr, 0);
    gemm_bt_kernel<1024, 1><<<dim3(2, (uint32_t)T), 256, 0, stream>>>(
        h, fc2b, nullptr, out, x, (int)(t0 * 128));
  }
}